// Round 3
// baseline (934.633 us; speedup 1.0000x reference)
//
#include <hip/hip_runtime.h>

#define DT_CONST 0.1f
constexpr int Q = 64;

// ---------------------------------------------------------------------------
// Kernel 1: node degrees via float atomics (exact for integer counts).
// ---------------------------------------------------------------------------
__global__ void deg_kernel(const int* __restrict__ src, const int* __restrict__ dst,
                           float* __restrict__ out_deg, float* __restrict__ in_deg,
                           int E) {
    int i = blockIdx.x * blockDim.x + threadIdx.x;
    int stride = gridDim.x * blockDim.x;
    for (int e = i; e < E; e += stride) {
        atomicAdd(&out_deg[src[e]], 1.0f);
        atomicAdd(&in_deg[dst[e]], 1.0f);
    }
}

// ---------------------------------------------------------------------------
// Kernel 2: per-edge scatter. One 64-lane wave per edge; lane = q component.
//   transport[src] += (w/in_deg[src])  * xi * (f[dst]-f[src])   (outflow)
//   transport[dst] -= (w/out_deg[src]) * xi * (f[dst]-f[src])   (inflow)
// transport lives in d_out (zeroed beforehand).
// ---------------------------------------------------------------------------
__global__ void scatter_kernel(const float* __restrict__ f,
                               const float* __restrict__ w,
                               const float* __restrict__ xi,
                               const int* __restrict__ src,
                               const int* __restrict__ dst,
                               const float* __restrict__ out_deg,
                               const float* __restrict__ in_deg,
                               float* __restrict__ transport,
                               int E) {
    int e = blockIdx.x * (blockDim.x >> 6) + (threadIdx.x >> 6);
    if (e >= E) return;
    int lane = threadIdx.x & 63;

    int s = src[e];
    int d = dst[e];
    float ww = w[e];
    float s_out = ww / fmaxf(in_deg[s], 1.0f);   // outflow scale (in_deg[src]!)
    float s_in  = ww / fmaxf(out_deg[s], 1.0f);  // inflow scale  (out_deg[src])

    float fs = fmaxf(f[(size_t)s * Q + lane], 0.0f);
    float fd = fmaxf(f[(size_t)d * Q + lane], 0.0f);
    float val = xi[lane] * (fd - fs);

    atomicAdd(&transport[(size_t)s * Q + lane],  s_out * val);
    atomicAdd(&transport[(size_t)d * Q + lane], -s_in  * val);
}

// ---------------------------------------------------------------------------
// Kernel 3: pointwise epilogue, float4-vectorized, in-place on d_out.
//   f_new = clip( clip(f,0) - DT*(transport - collision - source), 0 )
// ---------------------------------------------------------------------------
__global__ void final_kernel(const float* __restrict__ f,
                             const float* __restrict__ coll,
                             const float* __restrict__ srct,
                             float* __restrict__ out,   // holds transport on entry
                             int n4) {
    int i = blockIdx.x * blockDim.x + threadIdx.x;
    if (i >= n4) return;
    float4 t  = ((const float4*)out)[i];
    float4 fv = ((const float4*)f)[i];
    float4 c  = ((const float4*)coll)[i];
    float4 s  = ((const float4*)srct)[i];
    float4 r;
    r.x = fmaxf(fmaxf(fv.x, 0.0f) - DT_CONST * (t.x - c.x - s.x), 0.0f);
    r.y = fmaxf(fmaxf(fv.y, 0.0f) - DT_CONST * (t.y - c.y - s.y), 0.0f);
    r.z = fmaxf(fmaxf(fv.z, 0.0f) - DT_CONST * (t.z - c.z - s.z), 0.0f);
    r.w = fmaxf(fmaxf(fv.w, 0.0f) - DT_CONST * (t.w - c.w - s.w), 0.0f);
    ((float4*)out)[i] = r;
}

extern "C" void kernel_launch(void* const* d_in, const int* in_sizes, int n_in,
                              void* d_out, int out_size, void* d_ws, size_t ws_size,
                              hipStream_t stream) {
    const float* f    = (const float*)d_in[0];   // [N, 64]
    const float* coll = (const float*)d_in[1];   // [N, 64]
    const float* srct = (const float*)d_in[2];   // [N, 64]
    const float* w    = (const float*)d_in[3];   // [E]
    const float* xi   = (const float*)d_in[4];   // [64]
    const int*   eidx = (const int*)d_in[5];     // [2, E]

    int N = in_sizes[0] / Q;
    int E = in_sizes[3];
    const int* esrc = eidx;       // row 0
    const int* edst = eidx + E;   // row 1

    float* out     = (float*)d_out;          // transport accumulator, then f_new
    float* out_deg = (float*)d_ws;           // [N]
    float* in_deg  = out_deg + N;            // [N]

    // zero accumulators (ws/out are poisoned 0xAA before every call)
    hipMemsetAsync(out,  0, (size_t)N * Q * sizeof(float), stream);
    hipMemsetAsync(d_ws, 0, (size_t)2 * N * sizeof(float), stream);

    // 1) degrees
    deg_kernel<<<1024, 256, 0, stream>>>(esrc, edst, out_deg, in_deg, E);

    // 2) edge scatter: 4 edges per 256-thread block (one wave each)
    int epb = 256 / 64;
    int blocks = (E + epb - 1) / epb;
    scatter_kernel<<<blocks, 256, 0, stream>>>(f, w, xi, esrc, edst,
                                               out_deg, in_deg, out, E);

    // 3) epilogue
    int n4 = (N * Q) / 4;
    final_kernel<<<(n4 + 255) / 256, 256, 0, stream>>>(f, coll, srct, out, n4);
}

// Round 4
// 712.286 us; speedup vs baseline: 1.3122x; 1.3122x over previous
//
#include <hip/hip_runtime.h>

#define DT_CONST 0.1f
constexpr int Q = 64;
constexpr int SCAN_CHUNK = 1024;

// ===========================================================================
// CSR-gather path (primary).
// ===========================================================================

// --- count degrees (int atomics, L2-friendly: 2 x 400 KB counter arrays) ---
__global__ void count_kernel(const int* __restrict__ src, const int* __restrict__ dst,
                             int* __restrict__ cnt_out, int* __restrict__ cnt_in, int E) {
    int i = blockIdx.x * blockDim.x + threadIdx.x;
    int stride = gridDim.x * blockDim.x;
    for (int e = i; e < E; e += stride) {
        atomicAdd(&cnt_out[src[e]], 1);
        atomicAdd(&cnt_in[dst[e]], 1);
    }
}

// --- phase A: per-block exclusive scan (Hillis-Steele in LDS) --------------
// gridDim.x = 2*nblk: first nblk blocks scan cnt_out -> off_out, rest cnt_in.
__global__ void scanA_kernel(const int* __restrict__ cnt_out, const int* __restrict__ cnt_in,
                             int* __restrict__ off_out, int* __restrict__ off_in,
                             int* __restrict__ bsum, int nblk, int n) {
    int b = blockIdx.x;
    const int* cnt; int* off; int* bs;
    if (b < nblk) { cnt = cnt_out; off = off_out; bs = bsum; }
    else          { cnt = cnt_in;  off = off_in;  bs = bsum + nblk; b -= nblk; }
    int i = b * SCAN_CHUNK + threadIdx.x;
    __shared__ int tmp[SCAN_CHUNK];
    int v = (i < n) ? cnt[i] : 0;
    tmp[threadIdx.x] = v;
    __syncthreads();
    for (int s = 1; s < SCAN_CHUNK; s <<= 1) {
        int t = (threadIdx.x >= (unsigned)s) ? tmp[threadIdx.x - s] : 0;
        __syncthreads();
        tmp[threadIdx.x] += t;
        __syncthreads();
    }
    if (i < n) off[i] = tmp[threadIdx.x] - v;        // exclusive
    if (threadIdx.x == SCAN_CHUNK - 1) bs[b] = tmp[SCAN_CHUNK - 1];
}

// --- phase B: serial scan of block sums (2*nblk ~ 200 elements) ------------
__global__ void scanB_kernel(int* __restrict__ bsum, int nblk) {
    if (threadIdx.x == 0 && blockIdx.x == 0) {
        int c = 0;
        for (int i = 0; i < nblk; ++i) { int t = bsum[i]; bsum[i] = c; c += t; }
        c = 0;
        for (int i = nblk; i < 2 * nblk; ++i) { int t = bsum[i]; bsum[i] = c; c += t; }
    }
}

// --- phase C: add block offsets, init cursors ------------------------------
__global__ void scanC_kernel(int* __restrict__ off_out, int* __restrict__ off_in,
                             const int* __restrict__ bsum,
                             int* __restrict__ cur_out, int* __restrict__ cur_in,
                             int nblk, int n) {
    int b = blockIdx.x;
    bool isOut = b < nblk;
    int bb = isOut ? b : b - nblk;
    int i = bb * SCAN_CHUNK + threadIdx.x;
    if (i >= n) return;
    if (isOut) { int o = off_out[i] + bsum[b];        off_out[i] = o; cur_out[i] = o; }
    else       { int o = off_in[i]  + bsum[b];        off_in[i]  = o; cur_in[i]  = o; }
}

// --- fill adjacency: (neighbor, weight/scale) pairs ------------------------
__global__ void fill_kernel(const int* __restrict__ src, const int* __restrict__ dst,
                            const float* __restrict__ w, const int* __restrict__ cnt_out,
                            int* __restrict__ cur_out, int* __restrict__ cur_in,
                            int* __restrict__ nbr_out, float* __restrict__ w_out,
                            int* __restrict__ nbr_in, float* __restrict__ sc_in, int E) {
    int i = blockIdx.x * blockDim.x + threadIdx.x;
    int stride = gridDim.x * blockDim.x;
    for (int e = i; e < E; e += stride) {
        int s = src[e], d = dst[e];
        float ww = w[e];
        int p = atomicAdd(&cur_out[s], 1);
        nbr_out[p] = d;
        w_out[p] = ww;
        int q = atomicAdd(&cur_in[d], 1);
        nbr_in[q] = s;
        sc_in[q] = ww / (float)max(cnt_out[s], 1);   // w_e / out_deg[src_e]
    }
}

// --- fused gather + epilogue: one 64-lane wave per node, lane = q ----------
__global__ void gather_kernel(const float* __restrict__ f,
                              const float* __restrict__ coll,
                              const float* __restrict__ srct,
                              const float* __restrict__ xi,
                              const int* __restrict__ off_out, const int* __restrict__ cnt_out,
                              const int* __restrict__ nbr_out, const float* __restrict__ w_out,
                              const int* __restrict__ off_in, const int* __restrict__ cnt_in,
                              const int* __restrict__ nbr_in, const float* __restrict__ sc_in,
                              float* __restrict__ out, int N) {
    int v = blockIdx.x * (blockDim.x >> 6) + (threadIdx.x >> 6);
    if (v >= N) return;
    int lane = threadIdx.x & 63;

    float fv = fmaxf(f[(size_t)v * Q + lane], 0.0f);
    float acc_out = 0.0f, acc_in = 0.0f;

    // outflow: sum over out-edges of v: w_e * (f[dst_e] - f_v)
    int st = off_out[v], dg = cnt_out[v];
    for (int base = 0; base < dg; base += 64) {
        int m = min(64, dg - base);
        int nb = 0; float wv = 0.0f;
        if (lane < m) { nb = nbr_out[st + base + lane]; wv = w_out[st + base + lane]; }
        for (int j = 0; j < m; ++j) {
            int   n2 = __shfl(nb, j);
            float w2 = __shfl(wv, j);
            float fd = fmaxf(f[(size_t)n2 * Q + lane], 0.0f);
            acc_out += w2 * (fd - fv);
        }
    }

    // inflow: sum over in-edges of v: (w_e/out_deg[src_e]) * (f_v - f[src_e])
    st = off_in[v]; dg = cnt_in[v];
    for (int base = 0; base < dg; base += 64) {
        int m = min(64, dg - base);
        int nb = 0; float wv = 0.0f;
        if (lane < m) { nb = nbr_in[st + base + lane]; wv = sc_in[st + base + lane]; }
        for (int j = 0; j < m; ++j) {
            int   n2 = __shfl(nb, j);
            float w2 = __shfl(wv, j);
            float fs = fmaxf(f[(size_t)n2 * Q + lane], 0.0f);
            acc_in += w2 * (fv - fs);
        }
    }

    float indeg = (float)max(cnt_in[v], 1);
    float transport = xi[lane] * (acc_out / indeg - acc_in);

    size_t idx = (size_t)v * Q + lane;
    float r = fv - DT_CONST * (transport - coll[idx] - srct[idx]);
    out[idx] = fmaxf(r, 0.0f);
}

// ===========================================================================
// Fallback path (verified round-3 atomic scatter) — used if ws too small.
// ===========================================================================
__global__ void deg_kernel(const int* __restrict__ src, const int* __restrict__ dst,
                           float* __restrict__ out_deg, float* __restrict__ in_deg, int E) {
    int i = blockIdx.x * blockDim.x + threadIdx.x;
    int stride = gridDim.x * blockDim.x;
    for (int e = i; e < E; e += stride) {
        atomicAdd(&out_deg[src[e]], 1.0f);
        atomicAdd(&in_deg[dst[e]], 1.0f);
    }
}

__global__ void scatter_kernel(const float* __restrict__ f, const float* __restrict__ w,
                               const float* __restrict__ xi, const int* __restrict__ src,
                               const int* __restrict__ dst, const float* __restrict__ out_deg,
                               const float* __restrict__ in_deg, float* __restrict__ transport,
                               int E) {
    int e = blockIdx.x * (blockDim.x >> 6) + (threadIdx.x >> 6);
    if (e >= E) return;
    int lane = threadIdx.x & 63;
    int s = src[e], d = dst[e];
    float ww = w[e];
    float s_out = ww / fmaxf(in_deg[s], 1.0f);
    float s_in  = ww / fmaxf(out_deg[s], 1.0f);
    float fs = fmaxf(f[(size_t)s * Q + lane], 0.0f);
    float fd = fmaxf(f[(size_t)d * Q + lane], 0.0f);
    float val = xi[lane] * (fd - fs);
    atomicAdd(&transport[(size_t)s * Q + lane],  s_out * val);
    atomicAdd(&transport[(size_t)d * Q + lane], -s_in  * val);
}

__global__ void final_kernel(const float* __restrict__ f, const float* __restrict__ coll,
                             const float* __restrict__ srct, float* __restrict__ out, int n4) {
    int i = blockIdx.x * blockDim.x + threadIdx.x;
    if (i >= n4) return;
    float4 t  = ((const float4*)out)[i];
    float4 fv = ((const float4*)f)[i];
    float4 c  = ((const float4*)coll)[i];
    float4 s  = ((const float4*)srct)[i];
    float4 r;
    r.x = fmaxf(fmaxf(fv.x, 0.0f) - DT_CONST * (t.x - c.x - s.x), 0.0f);
    r.y = fmaxf(fmaxf(fv.y, 0.0f) - DT_CONST * (t.y - c.y - s.y), 0.0f);
    r.z = fmaxf(fmaxf(fv.z, 0.0f) - DT_CONST * (t.z - c.z - s.z), 0.0f);
    r.w = fmaxf(fmaxf(fv.w, 0.0f) - DT_CONST * (t.w - c.w - s.w), 0.0f);
    ((float4*)out)[i] = r;
}

// ===========================================================================
extern "C" void kernel_launch(void* const* d_in, const int* in_sizes, int n_in,
                              void* d_out, int out_size, void* d_ws, size_t ws_size,
                              hipStream_t stream) {
    const float* f    = (const float*)d_in[0];   // [N, 64]
    const float* coll = (const float*)d_in[1];   // [N, 64]
    const float* srct = (const float*)d_in[2];   // [N, 64]
    const float* w    = (const float*)d_in[3];   // [E]
    const float* xi   = (const float*)d_in[4];   // [64]
    const int*   eidx = (const int*)d_in[5];     // [2, E]

    int N = in_sizes[0] / Q;
    int E = in_sizes[3];
    const int* esrc = eidx;
    const int* edst = eidx + E;
    float* out = (float*)d_out;

    int nblk = (N + SCAN_CHUNK - 1) / SCAN_CHUNK;

    // workspace layout (all 4-byte elements)
    size_t need = ((size_t)6 * N + 2 * nblk + 256 + (size_t)4 * E) * 4;

    if (ws_size >= need) {
        int* cnt_out = (int*)d_ws;        // N
        int* cnt_in  = cnt_out + N;       // N
        int* off_out = cnt_in + N;        // N
        int* off_in  = off_out + N;       // N
        int* cur_out = off_in + N;        // N
        int* cur_in  = cur_out + N;       // N
        int* bsum    = cur_in + N;        // 2*nblk (+pad)
        int*   nbr_out = bsum + 2 * nblk + 256;  // E
        float* w_out   = (float*)(nbr_out + E);  // E
        int*   nbr_in  = (int*)(w_out + E);      // E
        float* sc_in   = (float*)(nbr_in + E);   // E

        hipMemsetAsync(cnt_out, 0, (size_t)2 * N * sizeof(int), stream);

        count_kernel<<<2048, 256, 0, stream>>>(esrc, edst, cnt_out, cnt_in, E);
        scanA_kernel<<<2 * nblk, SCAN_CHUNK, 0, stream>>>(cnt_out, cnt_in,
                                                          off_out, off_in, bsum, nblk, N);
        scanB_kernel<<<1, 64, 0, stream>>>(bsum, nblk);
        scanC_kernel<<<2 * nblk, SCAN_CHUNK, 0, stream>>>(off_out, off_in, bsum,
                                                          cur_out, cur_in, nblk, N);
        fill_kernel<<<2048, 256, 0, stream>>>(esrc, edst, w, cnt_out,
                                              cur_out, cur_in,
                                              nbr_out, w_out, nbr_in, sc_in, E);
        int nodes_per_block = 256 / 64;
        int gblocks = (N + nodes_per_block - 1) / nodes_per_block;
        gather_kernel<<<gblocks, 256, 0, stream>>>(f, coll, srct, (const float*)d_in[4],
                                                   off_out, cnt_out, nbr_out, w_out,
                                                   off_in, cnt_in, nbr_in, sc_in,
                                                   out, N);
    } else {
        // fallback: verified atomic-scatter path
        float* out_deg = (float*)d_ws;
        float* in_deg  = out_deg + N;
        hipMemsetAsync(out, 0, (size_t)N * Q * sizeof(float), stream);
        hipMemsetAsync(d_ws, 0, (size_t)2 * N * sizeof(float), stream);
        deg_kernel<<<1024, 256, 0, stream>>>(esrc, edst, out_deg, in_deg, E);
        int epb = 256 / 64;
        int blocks = (E + epb - 1) / epb;
        scatter_kernel<<<blocks, 256, 0, stream>>>(f, w, xi, esrc, edst,
                                                   out_deg, in_deg, out, E);
        int n4 = (N * Q) / 4;
        final_kernel<<<(n4 + 255) / 256, 256, 0, stream>>>(f, coll, srct, out, n4);
    }
}

// Round 6
// 597.056 us; speedup vs baseline: 1.5654x; 1.1930x over previous
//
#include <hip/hip_runtime.h>

#define DT_CONST 0.1f
constexpr int Q = 64;
constexpr int SCAN_CHUNK = 1024;

// ===========================================================================
// CSR-gather path (primary).
// ws layout: cnt_out[N], cnt_in[N], off_out[N], off_in[N], bsum[2*nblk+pad],
//            pair_out[E] (int2), pair_in[E] (int2)
// ===========================================================================

// --- count degrees (int atomics; 2 x 400 KB counter arrays, L2-resident) ---
__global__ void count_kernel(const int* __restrict__ src, const int* __restrict__ dst,
                             int* __restrict__ cnt_out, int* __restrict__ cnt_in, int E) {
    int i = blockIdx.x * blockDim.x + threadIdx.x;
    int stride = gridDim.x * blockDim.x;
    for (int e = i; e < E; e += stride) {
        atomicAdd(&cnt_out[src[e]], 1);
        atomicAdd(&cnt_in[dst[e]], 1);
    }
}

// --- phase A: per-block exclusive scan (Hillis-Steele in LDS) --------------
__global__ void scanA_kernel(const int* __restrict__ cnt_out, const int* __restrict__ cnt_in,
                             int* __restrict__ off_out, int* __restrict__ off_in,
                             int* __restrict__ bsum, int nblk, int n) {
    int b = blockIdx.x;
    const int* cnt; int* off; int* bs;
    if (b < nblk) { cnt = cnt_out; off = off_out; bs = bsum; }
    else          { cnt = cnt_in;  off = off_in;  bs = bsum + nblk; b -= nblk; }
    int i = b * SCAN_CHUNK + threadIdx.x;
    __shared__ int tmp[SCAN_CHUNK];
    int v = (i < n) ? cnt[i] : 0;
    tmp[threadIdx.x] = v;
    __syncthreads();
    for (int s = 1; s < SCAN_CHUNK; s <<= 1) {
        int t = (threadIdx.x >= (unsigned)s) ? tmp[threadIdx.x - s] : 0;
        __syncthreads();
        tmp[threadIdx.x] += t;
        __syncthreads();
    }
    if (i < n) off[i] = tmp[threadIdx.x] - v;        // exclusive
    if (threadIdx.x == SCAN_CHUNK - 1) bs[b] = tmp[SCAN_CHUNK - 1];
}

// --- phase B: PARALLEL scan of block sums (both directions, one block) -----
__global__ void scanB_kernel(int* __restrict__ bsum, int nblk) {
    __shared__ int tmp[SCAN_CHUNK];
    for (int dir = 0; dir < 2; ++dir) {
        int* bs = bsum + dir * nblk;
        int v = (threadIdx.x < (unsigned)nblk) ? bs[threadIdx.x] : 0;
        tmp[threadIdx.x] = v;
        __syncthreads();
        for (int s = 1; s < SCAN_CHUNK; s <<= 1) {
            int t = (threadIdx.x >= (unsigned)s) ? tmp[threadIdx.x - s] : 0;
            __syncthreads();
            tmp[threadIdx.x] += t;
            __syncthreads();
        }
        if (threadIdx.x < (unsigned)nblk) bs[threadIdx.x] = tmp[threadIdx.x] - v; // exclusive
        __syncthreads();
    }
}

// --- phase C: add block offsets to make global exclusive offsets -----------
__global__ void scanC_kernel(int* __restrict__ off_out, int* __restrict__ off_in,
                             const int* __restrict__ bsum, int nblk, int n) {
    int b = blockIdx.x;
    bool isOut = b < nblk;
    int bb = isOut ? b : b - nblk;
    int i = bb * SCAN_CHUNK + threadIdx.x;
    if (i >= n) return;
    if (isOut) off_out[i] += bsum[b];
    else       off_in[i]  += bsum[b];
}

// --- fill adjacency: one packed 8B (nbr, scale) store per direction --------
// Bumps off[] directly as the cursor; gather reconstructs start = off - cnt.
__global__ void fill_kernel(const int* __restrict__ src, const int* __restrict__ dst,
                            const float* __restrict__ w, const int* __restrict__ cnt_out,
                            int* __restrict__ off_out, int* __restrict__ off_in,
                            int2* __restrict__ pair_out, int2* __restrict__ pair_in, int E) {
    int i = blockIdx.x * blockDim.x + threadIdx.x;
    int stride = gridDim.x * blockDim.x;
    for (int e = i; e < E; e += stride) {
        int s = src[e], d = dst[e];
        float ww = w[e];
        int p = atomicAdd(&off_out[s], 1);
        pair_out[p] = make_int2(d, __float_as_int(ww));
        float sc = ww / (float)max(cnt_out[s], 1);   // w_e / out_deg[src_e]
        int q = atomicAdd(&off_in[d], 1);
        pair_in[q] = make_int2(s, __float_as_int(sc));
    }
}

// --- fused gather + epilogue: one 64-lane wave per node, lane = q ----------
// 4-way unrolled neighbor loop for memory-level parallelism.
__global__ void gather_kernel(const float* __restrict__ f,
                              const float* __restrict__ coll,
                              const float* __restrict__ srct,
                              const float* __restrict__ xi,
                              const int* __restrict__ off_out, const int* __restrict__ cnt_out,
                              const int2* __restrict__ pair_out,
                              const int* __restrict__ off_in, const int* __restrict__ cnt_in,
                              const int2* __restrict__ pair_in,
                              float* __restrict__ out, int N) {
    int v = blockIdx.x * (blockDim.x >> 6) + (threadIdx.x >> 6);
    if (v >= N) return;
    int lane = threadIdx.x & 63;

    float fv = fmaxf(f[(size_t)v * Q + lane], 0.0f);
    float acc_out = 0.0f, acc_in = 0.0f;

    // ---- outflow: out-edges of v: w_e * (f[dst_e] - f_v) ----
    {
        int dg = cnt_out[v];
        int st = off_out[v] - dg;          // off was bumped by fill
        for (int base = 0; base < dg; base += 64) {
            int m = min(64, dg - base);
            int2 pr = make_int2(0, 0);
            if (lane < m) pr = pair_out[st + base + lane];
            int j = 0;
            for (; j + 4 <= m; j += 4) {
                int   n0 = __shfl(pr.x, j),     n1 = __shfl(pr.x, j + 1);
                int   n2 = __shfl(pr.x, j + 2), n3 = __shfl(pr.x, j + 3);
                float w0 = __int_as_float(__shfl(pr.y, j));
                float w1 = __int_as_float(__shfl(pr.y, j + 1));
                float w2 = __int_as_float(__shfl(pr.y, j + 2));
                float w3 = __int_as_float(__shfl(pr.y, j + 3));
                float f0 = f[(size_t)n0 * Q + lane];
                float f1 = f[(size_t)n1 * Q + lane];
                float f2 = f[(size_t)n2 * Q + lane];
                float f3 = f[(size_t)n3 * Q + lane];
                acc_out += w0 * (fmaxf(f0, 0.0f) - fv);
                acc_out += w1 * (fmaxf(f1, 0.0f) - fv);
                acc_out += w2 * (fmaxf(f2, 0.0f) - fv);
                acc_out += w3 * (fmaxf(f3, 0.0f) - fv);
            }
            for (; j < m; ++j) {
                int   n2 = __shfl(pr.x, j);
                float w2 = __int_as_float(__shfl(pr.y, j));
                float fd = fmaxf(f[(size_t)n2 * Q + lane], 0.0f);
                acc_out += w2 * (fd - fv);
            }
        }
    }

    // ---- inflow: in-edges of v: (w_e/out_deg[src_e]) * (f_v - f[src_e]) ----
    {
        int dg = cnt_in[v];
        int st = off_in[v] - dg;
        for (int base = 0; base < dg; base += 64) {
            int m = min(64, dg - base);
            int2 pr = make_int2(0, 0);
            if (lane < m) pr = pair_in[st + base + lane];
            int j = 0;
            for (; j + 4 <= m; j += 4) {
                int   n0 = __shfl(pr.x, j),     n1 = __shfl(pr.x, j + 1);
                int   n2 = __shfl(pr.x, j + 2), n3 = __shfl(pr.x, j + 3);
                float w0 = __int_as_float(__shfl(pr.y, j));
                float w1 = __int_as_float(__shfl(pr.y, j + 1));
                float w2 = __int_as_float(__shfl(pr.y, j + 2));
                float w3 = __int_as_float(__shfl(pr.y, j + 3));
                float f0 = f[(size_t)n0 * Q + lane];
                float f1 = f[(size_t)n1 * Q + lane];
                float f2 = f[(size_t)n2 * Q + lane];
                float f3 = f[(size_t)n3 * Q + lane];
                acc_in += w0 * (fv - fmaxf(f0, 0.0f));
                acc_in += w1 * (fv - fmaxf(f1, 0.0f));
                acc_in += w2 * (fv - fmaxf(f2, 0.0f));
                acc_in += w3 * (fv - fmaxf(f3, 0.0f));
            }
            for (; j < m; ++j) {
                int   n2 = __shfl(pr.x, j);
                float w2 = __int_as_float(__shfl(pr.y, j));
                float fs = fmaxf(f[(size_t)n2 * Q + lane], 0.0f);
                acc_in += w2 * (fv - fs);
            }
        }
    }

    float indeg = (float)max(cnt_in[v], 1);
    float transport = xi[lane] * (acc_out / indeg - acc_in);

    size_t idx = (size_t)v * Q + lane;
    float r = fv - DT_CONST * (transport - coll[idx] - srct[idx]);
    out[idx] = fmaxf(r, 0.0f);
}

// ===========================================================================
// Fallback path (verified round-3 atomic scatter) — used if ws too small.
// ===========================================================================
__global__ void deg_kernel(const int* __restrict__ src, const int* __restrict__ dst,
                           float* __restrict__ out_deg, float* __restrict__ in_deg, int E) {
    int i = blockIdx.x * blockDim.x + threadIdx.x;
    int stride = gridDim.x * blockDim.x;
    for (int e = i; e < E; e += stride) {
        atomicAdd(&out_deg[src[e]], 1.0f);
        atomicAdd(&in_deg[dst[e]], 1.0f);
    }
}

__global__ void scatter_kernel(const float* __restrict__ f, const float* __restrict__ w,
                               const float* __restrict__ xi, const int* __restrict__ src,
                               const int* __restrict__ dst, const float* __restrict__ out_deg,
                               const float* __restrict__ in_deg, float* __restrict__ transport,
                               int E) {
    int e = blockIdx.x * (blockDim.x >> 6) + (threadIdx.x >> 6);
    if (e >= E) return;
    int lane = threadIdx.x & 63;
    int s = src[e], d = dst[e];
    float ww = w[e];
    float s_out = ww / fmaxf(in_deg[s], 1.0f);
    float s_in  = ww / fmaxf(out_deg[s], 1.0f);
    float fs = fmaxf(f[(size_t)s * Q + lane], 0.0f);
    float fd = fmaxf(f[(size_t)d * Q + lane], 0.0f);
    float val = xi[lane] * (fd - fs);
    atomicAdd(&transport[(size_t)s * Q + lane],  s_out * val);
    atomicAdd(&transport[(size_t)d * Q + lane], -s_in  * val);
}

__global__ void final_kernel(const float* __restrict__ f, const float* __restrict__ coll,
                             const float* __restrict__ srct, float* __restrict__ out, int n4) {
    int i = blockIdx.x * blockDim.x + threadIdx.x;
    if (i >= n4) return;
    float4 t  = ((const float4*)out)[i];
    float4 fv = ((const float4*)f)[i];
    float4 c  = ((const float4*)coll)[i];
    float4 s  = ((const float4*)srct)[i];
    float4 r;
    r.x = fmaxf(fmaxf(fv.x, 0.0f) - DT_CONST * (t.x - c.x - s.x), 0.0f);
    r.y = fmaxf(fmaxf(fv.y, 0.0f) - DT_CONST * (t.y - c.y - s.y), 0.0f);
    r.z = fmaxf(fmaxf(fv.z, 0.0f) - DT_CONST * (t.z - c.z - s.z), 0.0f);
    r.w = fmaxf(fmaxf(fv.w, 0.0f) - DT_CONST * (t.w - c.w - s.w), 0.0f);
    ((float4*)out)[i] = r;
}

// ===========================================================================
extern "C" void kernel_launch(void* const* d_in, const int* in_sizes, int n_in,
                              void* d_out, int out_size, void* d_ws, size_t ws_size,
                              hipStream_t stream) {
    const float* f    = (const float*)d_in[0];   // [N, 64]
    const float* coll = (const float*)d_in[1];   // [N, 64]
    const float* srct = (const float*)d_in[2];   // [N, 64]
    const float* w    = (const float*)d_in[3];   // [E]
    const float* xi   = (const float*)d_in[4];   // [64]
    const int*   eidx = (const int*)d_in[5];     // [2, E]

    int N = in_sizes[0] / Q;
    int E = in_sizes[3];
    const int* esrc = eidx;
    const int* edst = eidx + E;
    float* out = (float*)d_out;

    int nblk = (N + SCAN_CHUNK - 1) / SCAN_CHUNK;

    // workspace: 4N (cnt/off) + 2*nblk+pad (bsum) + 4E (two int2 pair arrays)
    size_t need = ((size_t)4 * N + 2 * nblk + 256 + (size_t)4 * E) * 4;

    if (ws_size >= need) {
        int* cnt_out = (int*)d_ws;                 // N
        int* cnt_in  = cnt_out + N;                // N
        int* off_out = cnt_in + N;                 // N
        int* off_in  = off_out + N;                // N
        int* bsum    = off_in + N;                 // 2*nblk (+pad)
        int2* pair_out = (int2*)(bsum + 2 * nblk + 256);  // E
        int2* pair_in  = pair_out + E;                    // E

        hipMemsetAsync(cnt_out, 0, (size_t)2 * N * sizeof(int), stream);

        count_kernel<<<2048, 256, 0, stream>>>(esrc, edst, cnt_out, cnt_in, E);
        scanA_kernel<<<2 * nblk, SCAN_CHUNK, 0, stream>>>(cnt_out, cnt_in,
                                                          off_out, off_in, bsum, nblk, N);
        scanB_kernel<<<1, SCAN_CHUNK, 0, stream>>>(bsum, nblk);
        scanC_kernel<<<2 * nblk, SCAN_CHUNK, 0, stream>>>(off_out, off_in, bsum, nblk, N);
        fill_kernel<<<2048, 256, 0, stream>>>(esrc, edst, w, cnt_out,
                                              off_out, off_in, pair_out, pair_in, E);
        int nodes_per_block = 256 / 64;
        int gblocks = (N + nodes_per_block - 1) / nodes_per_block;
        gather_kernel<<<gblocks, 256, 0, stream>>>(f, coll, srct, (const float*)d_in[4],
                                                   off_out, cnt_out, pair_out,
                                                   off_in, cnt_in, pair_in,
                                                   out, N);
    } else {
        // fallback: verified atomic-scatter path
        float* out_deg = (float*)d_ws;
        float* in_deg  = out_deg + N;
        hipMemsetAsync(out, 0, (size_t)N * Q * sizeof(float), stream);
        hipMemsetAsync(d_ws, 0, (size_t)2 * N * sizeof(float), stream);
        deg_kernel<<<1024, 256, 0, stream>>>(esrc, edst, out_deg, in_deg, E);
        int epb = 256 / 64;
        int blocks = (E + epb - 1) / epb;
        scatter_kernel<<<blocks, 256, 0, stream>>>(f, w, xi, esrc, edst,
                                                   out_deg, in_deg, out, E);
        int n4 = (N * Q) / 4;
        final_kernel<<<(n4 + 255) / 256, 256, 0, stream>>>(f, coll, srct, out, n4);
    }
}